// Round 10
// baseline (492.917 us; speedup 1.0000x reference)
//
#include <hip/hip_runtime.h>
#include <math.h>

typedef float    f32x4 __attribute__((ext_vector_type(4)));
typedef short    s16x8 __attribute__((ext_vector_type(8)));
typedef _Float16 h2    __attribute__((ext_vector_type(2)));
typedef __fp16   g2    __attribute__((ext_vector_type(2)));  // cvt_pkrtz result type

#define N_TOT 16384
#define C_TOT 1000
#define C_PAD 1024
#define D_TOT 512
#define NC ((size_t)N_TOT * C_TOT)

#define EPS_F 1e-8f
#define SCALE_F 0.04419417382415922f  // 1/sqrt(512)

#define GL_LDS(gp, lp)                                                        \
    __builtin_amdgcn_global_load_lds(                                         \
        (const __attribute__((address_space(1))) void*)(gp),                  \
        (__attribute__((address_space(3))) void*)(lp), 16, 0, 0)

// ---------------- fsq / csq precompute: one wave per row ----------------
__global__ __launch_bounds__(256)
void sq_kernel(const float* __restrict__ F, const float* __restrict__ Cc,
               float* __restrict__ sqout) {
    int gw   = (blockIdx.x * 256 + threadIdx.x) >> 6;
    int lane = threadIdx.x & 63;
    if (gw >= N_TOT + C_TOT) return;
    const float* src = (gw < N_TOT) ? (F + (size_t)gw * D_TOT)
                                    : (Cc + (size_t)(gw - N_TOT) * D_TOT);
    f32x4 a = *(const f32x4*)(src + lane * 4);
    f32x4 b = *(const f32x4*)(src + 256 + lane * 4);
    float acc = a[0] * a[0];
    acc = fmaf(a[1], a[1], acc);
    acc = fmaf(a[2], a[2], acc);
    acc = fmaf(a[3], a[3], acc);
    acc = fmaf(b[0], b[0], acc);
    acc = fmaf(b[1], b[1], acc);
    acc = fmaf(b[2], b[2], acc);
    acc = fmaf(b[3], b[3], acc);
    #pragma unroll
    for (int off = 32; off > 0; off >>= 1)
        acc += __shfl_xor(acc, off);
    if (lane == 0) sqout[gw] = acc;
}

// ---------------- f32 -> bf16 (RNE) convert, C zero-padded to 1024 rows ----
__device__ inline short f2bf(float x) {
    union { float f; unsigned u; } v; v.f = x;
    unsigned r = (v.u + 0x7FFFu + ((v.u >> 16) & 1u)) >> 16;
    return (short)r;
}

__global__ __launch_bounds__(256)
void cvt_kernel(const float* __restrict__ F, const float* __restrict__ Cc,
                short* __restrict__ Fbf, short* __restrict__ Cbf) {
    const int FS8 = N_TOT * D_TOT / 8;   // 1048576
    const int CS8 = C_PAD * D_TOT / 8;   // 65536
    int gid = blockIdx.x * 256 + threadIdx.x;
    if (gid < FS8) {
        const float* s = F + (size_t)gid * 8;
        f32x4 a = *(const f32x4*)s;
        f32x4 b = *(const f32x4*)(s + 4);
        s16x8 o;
        o[0] = f2bf(a[0]); o[1] = f2bf(a[1]); o[2] = f2bf(a[2]); o[3] = f2bf(a[3]);
        o[4] = f2bf(b[0]); o[5] = f2bf(b[1]); o[6] = f2bf(b[2]); o[7] = f2bf(b[3]);
        *(s16x8*)(Fbf + (size_t)gid * 8) = o;
    } else if (gid < FS8 + CS8) {
        int j = gid - FS8;
        int base = j * 8;
        int crow = base >> 9;
        s16x8 o = (s16x8)(short)0;
        if (crow < C_TOT) {
            const float* s = Cc + (size_t)base;
            f32x4 a = *(const f32x4*)s;
            f32x4 b = *(const f32x4*)(s + 4);
            o[0] = f2bf(a[0]); o[1] = f2bf(a[1]); o[2] = f2bf(a[2]); o[3] = f2bf(a[3]);
            o[4] = f2bf(b[0]); o[5] = f2bf(b[1]); o[6] = f2bf(b[2]); o[7] = f2bf(b[3]);
        }
        *(s16x8*)(Cbf + (size_t)base) = o;
    }
}

// ---------------- bf16 MFMA dot GEMM -> writes L2 and cos (R4-validated) ---
__global__ __launch_bounds__(256)
void dot_gemm(const short* __restrict__ Fbf, const short* __restrict__ Cbf,
              const float* __restrict__ sqbuf, float* __restrict__ out) {
    __shared__ short lds[2][8192];   // A: [0,4096), B: [4096,8192)

    const int tid  = threadIdx.x;
    const int lane = tid & 63;
    const int wid  = tid >> 6;
    const int wr   = wid >> 1;
    const int wc   = wid & 1;
    const int m0   = blockIdx.y * 128;
    const int n0   = blockIdx.x * 128;

    const int row0 = tid >> 2;
    const int row1 = row0 + 64;
    const int slot = tid & 3;
    const int sw0  = slot ^ ((row0 >> 1) & 3);
    const int sw1  = slot ^ ((row1 >> 1) & 3);
    const short* sA0 = Fbf + (size_t)(m0 + row0) * D_TOT + sw0 * 8;
    const short* sA1 = Fbf + (size_t)(m0 + row1) * D_TOT + sw1 * 8;
    const short* sB0 = Cbf + (size_t)(n0 + row0) * D_TOT + sw0 * 8;
    const short* sB1 = Cbf + (size_t)(n0 + row1) * D_TOT + sw1 * 8;

    int offA[4], offB[4];
    #pragma unroll
    for (int fi = 0; fi < 4; ++fi) {
        int R = wr * 64 + fi * 16 + (lane & 15);
        offA[fi] = R * 32 + (((lane >> 4) ^ ((R >> 1) & 3)) << 3);
    }
    #pragma unroll
    for (int fj = 0; fj < 4; ++fj) {
        int R = wc * 64 + fj * 16 + (lane & 15);
        offB[fj] = 4096 + R * 32 + (((lane >> 4) ^ ((R >> 1) & 3)) << 3);
    }

    f32x4 acc[4][4];
    #pragma unroll
    for (int fi = 0; fi < 4; ++fi)
        #pragma unroll
        for (int fj = 0; fj < 4; ++fj) acc[fi][fj] = (f32x4)(0.f);

    GL_LDS(sA0, &lds[0][(size_t)tid * 8]);
    GL_LDS(sA1, &lds[0][(size_t)(tid + 256) * 8]);
    GL_LDS(sB0, &lds[0][4096 + (size_t)tid * 8]);
    GL_LDS(sB1, &lds[0][4096 + (size_t)(tid + 256) * 8]);
    __syncthreads();

    const int NK = D_TOT / 32;   // 16
    for (int kt = 0; kt < NK; ++kt) {
        if (kt + 1 < NK) {
            const int nb = (kt + 1) & 1;
            const int d1 = (kt + 1) * 32;
            GL_LDS(sA0 + d1, &lds[nb][(size_t)tid * 8]);
            GL_LDS(sA1 + d1, &lds[nb][(size_t)(tid + 256) * 8]);
            GL_LDS(sB0 + d1, &lds[nb][4096 + (size_t)tid * 8]);
            GL_LDS(sB1 + d1, &lds[nb][4096 + (size_t)(tid + 256) * 8]);
        }
        const short* lb = lds[kt & 1];
        s16x8 af[4], bg[4];
        #pragma unroll
        for (int fi = 0; fi < 4; ++fi) af[fi] = *(const s16x8*)&lb[offA[fi]];
        #pragma unroll
        for (int fj = 0; fj < 4; ++fj) bg[fj] = *(const s16x8*)&lb[offB[fj]];
        #pragma unroll
        for (int fi = 0; fi < 4; ++fi)
            #pragma unroll
            for (int fj = 0; fj < 4; ++fj)
                acc[fi][fj] = __builtin_amdgcn_mfma_f32_16x16x32_bf16(
                    af[fi], bg[fj], acc[fi][fj], 0, 0, 0);
        __syncthreads();
    }

    // epilogue: D layout col = lane&15, row = 4*(lane>>4) + reg  [m89/m91]
    const float* csq = sqbuf + N_TOT;
    float fs_[4][4], fn_[4][4];
    #pragma unroll
    for (int fi = 0; fi < 4; ++fi)
        #pragma unroll
        for (int reg = 0; reg < 4; ++reg) {
            int m = m0 + wr * 64 + fi * 16 + ((lane >> 4) << 2) + reg;
            float v = sqbuf[m];
            fs_[fi][reg] = v;
            fn_[fi][reg] = fmaxf(sqrtf(v), EPS_F);
        }
    #pragma unroll
    for (int fj = 0; fj < 4; ++fj) {
        int c = n0 + wc * 64 + fj * 16 + (lane & 15);
        if (c < C_TOT) {
            float cs = csq[c];
            float cn = fmaxf(sqrtf(cs), EPS_F);
            #pragma unroll
            for (int fi = 0; fi < 4; ++fi) {
                int mrow = m0 + wr * 64 + fi * 16 + ((lane >> 4) << 2);
                #pragma unroll
                for (int reg = 0; reg < 4; ++reg) {
                    float d = acc[fi][fj][reg];
                    size_t p = (size_t)(mrow + reg) * C_TOT + c;
                    float sqv = fmaxf(fs_[fi][reg] + cs - 2.0f * d, 0.f);
                    out[NC + p]     = sqrtf(sqv) * SCALE_F;
                    out[2 * NC + p] = (d * SCALE_F) / (fn_[fi][reg] * cn);
                }
            }
        }
    }
}

// ---------------- L1-only kernel: R8 structure, packed-f16 inner loop ------
// LDS rows of 16 f32 (64 B): rows 0..127 = F, 128..191 = C. C source-swizzled
// (slot s of row r holds k-slot s ^ ((r>>2)&3)); measured 0 bank conflicts.
// Inner compute: f32x4 -> 2x h2 (v_cvt_pkrtz), then per pair
// v_pk_add_f16(neg) + v_and_b32 + v_dot2_f32_f16 -> 3 insts / 2 elems.
__device__ inline h2 pkrtz(float a, float b) {
    return __builtin_bit_cast(h2, __builtin_amdgcn_cvt_pkrtz(a, b));
}

__device__ inline float absdot2(h2 f, h2 c, float acc) {
    h2 d = f - c;
    unsigned du = __builtin_bit_cast(unsigned, d) & 0x7FFF7FFFu;
    const h2 ones = {(_Float16)1.0f, (_Float16)1.0f};
    return __builtin_amdgcn_fdot2(__builtin_bit_cast(h2, du), ones, acc, false);
}

__global__ __launch_bounds__(256)
void l1_main(const float* __restrict__ F, const float* __restrict__ Cc,
             float* __restrict__ out) {
    __shared__ float lds[2][192 * 16];

    const int tid = threadIdx.x;
    const int tx  = tid & 15;    // centroid dir: cols tx + 16*j
    const int ty  = tid >> 4;    // feature dir:  rows ty + 16*i
    const int c0  = blockIdx.x * 64;
    const int n0  = blockIdx.y * 128;

    const int srow  = tid >> 2;        // 0..63
    const int sslot = tid & 3;
    const int w16   = (tid >> 6) * 16;

    const float* fA = F + (size_t)(n0 + srow) * D_TOT + sslot * 4;
    const float* fB = fA + (size_t)64 * D_TOT;
    const int cswz  = sslot ^ ((srow >> 2) & 3);
    const float* cP = Cc + (size_t)(c0 + srow) * D_TOT + cswz * 4;
    const bool cok  = (c0 + srow) < C_TOT;

    f32x4 l1v[8];
    #pragma unroll
    for (int i = 0; i < 8; ++i) l1v[i] = (f32x4)(0.f);

    GL_LDS(fA, &lds[0][w16 * 16]);
    GL_LDS(fB, &lds[0][(64 + w16) * 16]);
    if (cok) GL_LDS(cP, &lds[0][(128 + w16) * 16]);
    __syncthreads();

    const int NT  = 32;
    const int crs = (tx >> 2) & 3;

    for (int t = 0; t < NT; ++t) {
        if (t + 1 < NT) {
            const int nb = (t + 1) & 1;
            const int d1 = (t + 1) * 16;
            GL_LDS(fA + d1, &lds[nb][w16 * 16]);
            GL_LDS(fB + d1, &lds[nb][(64 + w16) * 16]);
            if (cok) GL_LDS(cP + d1, &lds[nb][(128 + w16) * 16]);
        }

        const float* lf = &lds[t & 1][0];
        #pragma unroll
        for (int q = 0; q < 4; ++q) {
            const int cq = (q ^ crs) << 2;
            f32x4 cv0 = *(const f32x4*)&lf[(128 + tx) * 16 + cq];
            f32x4 cv1 = *(const f32x4*)&lf[(128 + tx + 16) * 16 + cq];
            f32x4 cv2 = *(const f32x4*)&lf[(128 + tx + 32) * 16 + cq];
            f32x4 cv3 = *(const f32x4*)&lf[(128 + tx + 48) * 16 + cq];
            // pack centroid pairs once per q (reused across 8 i)
            h2 c0l = pkrtz(cv0[0], cv0[1]);
            h2 c0h = pkrtz(cv0[2], cv0[3]);
            h2 c1l = pkrtz(cv1[0], cv1[1]);
            h2 c1h = pkrtz(cv1[2], cv1[3]);
            h2 c2l = pkrtz(cv2[0], cv2[1]);
            h2 c2h = pkrtz(cv2[2], cv2[3]);
            h2 c3l = pkrtz(cv3[0], cv3[1]);
            h2 c3h = pkrtz(cv3[2], cv3[3]);
            #pragma unroll
            for (int i = 0; i < 8; ++i) {
                f32x4 fv = *(const f32x4*)&lf[((ty + 16 * i) << 4) + (q << 2)];
                h2 f0 = pkrtz(fv[0], fv[1]);
                h2 f1 = pkrtz(fv[2], fv[3]);
                float a0 = l1v[i][0], a1 = l1v[i][1];
                float a2 = l1v[i][2], a3 = l1v[i][3];
                a0 = absdot2(f0, c0l, a0);
                a1 = absdot2(f0, c1l, a1);
                a2 = absdot2(f0, c2l, a2);
                a3 = absdot2(f0, c3l, a3);
                a0 = absdot2(f1, c0h, a0);
                a1 = absdot2(f1, c1h, a1);
                a2 = absdot2(f1, c2h, a2);
                a3 = absdot2(f1, c3h, a3);
                l1v[i][0] = a0; l1v[i][1] = a1;
                l1v[i][2] = a2; l1v[i][3] = a3;
            }
        }
        __syncthreads();
    }

    #pragma unroll
    for (int i = 0; i < 8; ++i) {
        const size_t rb = (size_t)(n0 + ty + 16 * i) * C_TOT;
        #pragma unroll
        for (int j = 0; j < 4; ++j) {
            const int c = c0 + tx + 16 * j;
            if (c < C_TOT) out[rb + c] = l1v[i][j] * SCALE_F;
        }
    }
}

extern "C" void kernel_launch(void* const* d_in, const int* in_sizes, int n_in,
                              void* d_out, int out_size, void* d_ws, size_t ws_size,
                              hipStream_t stream) {
    const float* F  = (const float*)d_in[0];
    const float* Cc = (const float*)d_in[1];
    float* out   = (float*)d_out;
    float* sqbuf = (float*)d_ws;                 // [N_TOT + C_TOT] f32

    // bf16 scratch parked in the (not-yet-written) L1 region of out:
    // 17.8 MB < NC*4 B = 65.5 MB; dot_gemm reads it and writes only L2/cos
    // regions; l1_main overwrites the L1 region afterwards. (R4-validated.)
    short* Fbf = (short*)out;
    short* Cbf = Fbf + (size_t)N_TOT * D_TOT;

    int rows = N_TOT + C_TOT;
    sq_kernel<<<(rows + 3) / 4, 256, 0, stream>>>(F, Cc, sqbuf);
    cvt_kernel<<<(N_TOT * D_TOT / 8 + C_PAD * D_TOT / 8 + 255) / 256, 256, 0,
                 stream>>>(F, Cc, Fbf, Cbf);
    dot_gemm<<<dim3(8, 128), 256, 0, stream>>>(Fbf, Cbf, sqbuf, out);
    l1_main<<<dim3(16, 128), 256, 0, stream>>>(F, Cc, out);
}

// Round 11
// 464.697 us; speedup vs baseline: 1.0607x; 1.0607x over previous
//
#include <hip/hip_runtime.h>
#include <math.h>

typedef float    f32x4 __attribute__((ext_vector_type(4)));
typedef unsigned u32x4 __attribute__((ext_vector_type(4)));
typedef short    s16x8 __attribute__((ext_vector_type(8)));
typedef _Float16 h2    __attribute__((ext_vector_type(2)));

#define N_TOT 16384
#define C_TOT 1000
#define C_PAD 1024
#define D_TOT 512
#define NC ((size_t)N_TOT * C_TOT)

#define EPS_F 1e-8f
#define SCALE_F 0.04419417382415922f  // 1/sqrt(512)

#define GL_LDS(gp, lp)                                                        \
    __builtin_amdgcn_global_load_lds(                                         \
        (const __attribute__((address_space(1))) void*)(gp),                  \
        (__attribute__((address_space(3))) void*)(lp), 16, 0, 0)

// ---------------- fsq / csq precompute: one wave per row ----------------
__global__ __launch_bounds__(256)
void sq_kernel(const float* __restrict__ F, const float* __restrict__ Cc,
               float* __restrict__ sqout) {
    int gw   = (blockIdx.x * 256 + threadIdx.x) >> 6;
    int lane = threadIdx.x & 63;
    if (gw >= N_TOT + C_TOT) return;
    const float* src = (gw < N_TOT) ? (F + (size_t)gw * D_TOT)
                                    : (Cc + (size_t)(gw - N_TOT) * D_TOT);
    f32x4 a = *(const f32x4*)(src + lane * 4);
    f32x4 b = *(const f32x4*)(src + 256 + lane * 4);
    float acc = a[0] * a[0];
    acc = fmaf(a[1], a[1], acc);
    acc = fmaf(a[2], a[2], acc);
    acc = fmaf(a[3], a[3], acc);
    acc = fmaf(b[0], b[0], acc);
    acc = fmaf(b[1], b[1], acc);
    acc = fmaf(b[2], b[2], acc);
    acc = fmaf(b[3], b[3], acc);
    #pragma unroll
    for (int off = 32; off > 0; off >>= 1)
        acc += __shfl_xor(acc, off);
    if (lane == 0) sqout[gw] = acc;
}

// ---------------- f32 -> bf16 (RNE) convert, C zero-padded to 1024 rows ----
__device__ inline short f2bf(float x) {
    union { float f; unsigned u; } v; v.f = x;
    unsigned r = (v.u + 0x7FFFu + ((v.u >> 16) & 1u)) >> 16;
    return (short)r;
}

__global__ __launch_bounds__(256)
void cvt_kernel(const float* __restrict__ F, const float* __restrict__ Cc,
                short* __restrict__ Fbf, short* __restrict__ Cbf) {
    const int FS8 = N_TOT * D_TOT / 8;   // 1048576
    const int CS8 = C_PAD * D_TOT / 8;   // 65536
    int gid = blockIdx.x * 256 + threadIdx.x;
    if (gid < FS8) {
        const float* s = F + (size_t)gid * 8;
        f32x4 a = *(const f32x4*)s;
        f32x4 b = *(const f32x4*)(s + 4);
        s16x8 o;
        o[0] = f2bf(a[0]); o[1] = f2bf(a[1]); o[2] = f2bf(a[2]); o[3] = f2bf(a[3]);
        o[4] = f2bf(b[0]); o[5] = f2bf(b[1]); o[6] = f2bf(b[2]); o[7] = f2bf(b[3]);
        *(s16x8*)(Fbf + (size_t)gid * 8) = o;
    } else if (gid < FS8 + CS8) {
        int j = gid - FS8;
        int base = j * 8;
        int crow = base >> 9;
        s16x8 o = (s16x8)(short)0;
        if (crow < C_TOT) {
            const float* s = Cc + (size_t)base;
            f32x4 a = *(const f32x4*)s;
            f32x4 b = *(const f32x4*)(s + 4);
            o[0] = f2bf(a[0]); o[1] = f2bf(a[1]); o[2] = f2bf(a[2]); o[3] = f2bf(a[3]);
            o[4] = f2bf(b[0]); o[5] = f2bf(b[1]); o[6] = f2bf(b[2]); o[7] = f2bf(b[3]);
        }
        *(s16x8*)(Cbf + (size_t)base) = o;
    }
}

// ---------------- f32 -> f16 (RTZ pkrtz) copies for the L1 kernel ----------
__global__ __launch_bounds__(256)
void cvt16_kernel(const float* __restrict__ F, const float* __restrict__ Cc,
                  short* __restrict__ Ff16, short* __restrict__ Cf16) {
    const int FS8 = N_TOT * D_TOT / 8;
    const int CS8 = C_PAD * D_TOT / 8;
    int gid = blockIdx.x * 256 + threadIdx.x;
    if (gid < FS8) {
        const float* s = F + (size_t)gid * 8;
        f32x4 a = *(const f32x4*)s;
        f32x4 b = *(const f32x4*)(s + 4);
        u32x4 w;
        w[0] = __builtin_bit_cast(unsigned, __builtin_amdgcn_cvt_pkrtz(a[0], a[1]));
        w[1] = __builtin_bit_cast(unsigned, __builtin_amdgcn_cvt_pkrtz(a[2], a[3]));
        w[2] = __builtin_bit_cast(unsigned, __builtin_amdgcn_cvt_pkrtz(b[0], b[1]));
        w[3] = __builtin_bit_cast(unsigned, __builtin_amdgcn_cvt_pkrtz(b[2], b[3]));
        *(u32x4*)(Ff16 + (size_t)gid * 8) = w;
    } else if (gid < FS8 + CS8) {
        int j = gid - FS8;
        int base = j * 8;
        int crow = base >> 9;
        u32x4 w = (u32x4)(0u);
        if (crow < C_TOT) {
            const float* s = Cc + (size_t)base;
            f32x4 a = *(const f32x4*)s;
            f32x4 b = *(const f32x4*)(s + 4);
            w[0] = __builtin_bit_cast(unsigned, __builtin_amdgcn_cvt_pkrtz(a[0], a[1]));
            w[1] = __builtin_bit_cast(unsigned, __builtin_amdgcn_cvt_pkrtz(a[2], a[3]));
            w[2] = __builtin_bit_cast(unsigned, __builtin_amdgcn_cvt_pkrtz(b[0], b[1]));
            w[3] = __builtin_bit_cast(unsigned, __builtin_amdgcn_cvt_pkrtz(b[2], b[3]));
        }
        *(u32x4*)(Cf16 + (size_t)base) = w;
    }
}

// ---------------- bf16 MFMA dot GEMM -> writes L2 and cos (R4-validated) ---
__global__ __launch_bounds__(256)
void dot_gemm(const short* __restrict__ Fbf, const short* __restrict__ Cbf,
              const float* __restrict__ sqbuf, float* __restrict__ out) {
    __shared__ short lds[2][8192];   // A: [0,4096), B: [4096,8192)

    const int tid  = threadIdx.x;
    const int lane = tid & 63;
    const int wid  = tid >> 6;
    const int wr   = wid >> 1;
    const int wc   = wid & 1;
    const int m0   = blockIdx.y * 128;
    const int n0   = blockIdx.x * 128;

    const int row0 = tid >> 2;
    const int row1 = row0 + 64;
    const int slot = tid & 3;
    const int sw0  = slot ^ ((row0 >> 1) & 3);
    const int sw1  = slot ^ ((row1 >> 1) & 3);
    const short* sA0 = Fbf + (size_t)(m0 + row0) * D_TOT + sw0 * 8;
    const short* sA1 = Fbf + (size_t)(m0 + row1) * D_TOT + sw1 * 8;
    const short* sB0 = Cbf + (size_t)(n0 + row0) * D_TOT + sw0 * 8;
    const short* sB1 = Cbf + (size_t)(n0 + row1) * D_TOT + sw1 * 8;

    int offA[4], offB[4];
    #pragma unroll
    for (int fi = 0; fi < 4; ++fi) {
        int R = wr * 64 + fi * 16 + (lane & 15);
        offA[fi] = R * 32 + (((lane >> 4) ^ ((R >> 1) & 3)) << 3);
    }
    #pragma unroll
    for (int fj = 0; fj < 4; ++fj) {
        int R = wc * 64 + fj * 16 + (lane & 15);
        offB[fj] = 4096 + R * 32 + (((lane >> 4) ^ ((R >> 1) & 3)) << 3);
    }

    f32x4 acc[4][4];
    #pragma unroll
    for (int fi = 0; fi < 4; ++fi)
        #pragma unroll
        for (int fj = 0; fj < 4; ++fj) acc[fi][fj] = (f32x4)(0.f);

    GL_LDS(sA0, &lds[0][(size_t)tid * 8]);
    GL_LDS(sA1, &lds[0][(size_t)(tid + 256) * 8]);
    GL_LDS(sB0, &lds[0][4096 + (size_t)tid * 8]);
    GL_LDS(sB1, &lds[0][4096 + (size_t)(tid + 256) * 8]);
    __syncthreads();

    const int NK = D_TOT / 32;   // 16
    for (int kt = 0; kt < NK; ++kt) {
        if (kt + 1 < NK) {
            const int nb = (kt + 1) & 1;
            const int d1 = (kt + 1) * 32;
            GL_LDS(sA0 + d1, &lds[nb][(size_t)tid * 8]);
            GL_LDS(sA1 + d1, &lds[nb][(size_t)(tid + 256) * 8]);
            GL_LDS(sB0 + d1, &lds[nb][4096 + (size_t)tid * 8]);
            GL_LDS(sB1 + d1, &lds[nb][4096 + (size_t)(tid + 256) * 8]);
        }
        const short* lb = lds[kt & 1];
        s16x8 af[4], bg[4];
        #pragma unroll
        for (int fi = 0; fi < 4; ++fi) af[fi] = *(const s16x8*)&lb[offA[fi]];
        #pragma unroll
        for (int fj = 0; fj < 4; ++fj) bg[fj] = *(const s16x8*)&lb[offB[fj]];
        #pragma unroll
        for (int fi = 0; fi < 4; ++fi)
            #pragma unroll
            for (int fj = 0; fj < 4; ++fj)
                acc[fi][fj] = __builtin_amdgcn_mfma_f32_16x16x32_bf16(
                    af[fi], bg[fj], acc[fi][fj], 0, 0, 0);
        __syncthreads();
    }

    // epilogue: D layout col = lane&15, row = 4*(lane>>4) + reg  [m89/m91]
    const float* csq = sqbuf + N_TOT;
    float fs_[4][4], fn_[4][4];
    #pragma unroll
    for (int fi = 0; fi < 4; ++fi)
        #pragma unroll
        for (int reg = 0; reg < 4; ++reg) {
            int m = m0 + wr * 64 + fi * 16 + ((lane >> 4) << 2) + reg;
            float v = sqbuf[m];
            fs_[fi][reg] = v;
            fn_[fi][reg] = fmaxf(sqrtf(v), EPS_F);
        }
    #pragma unroll
    for (int fj = 0; fj < 4; ++fj) {
        int c = n0 + wc * 64 + fj * 16 + (lane & 15);
        if (c < C_TOT) {
            float cs = csq[c];
            float cn = fmaxf(sqrtf(cs), EPS_F);
            #pragma unroll
            for (int fi = 0; fi < 4; ++fi) {
                int mrow = m0 + wr * 64 + fi * 16 + ((lane >> 4) << 2);
                #pragma unroll
                for (int reg = 0; reg < 4; ++reg) {
                    float d = acc[fi][fj][reg];
                    size_t p = (size_t)(mrow + reg) * C_TOT + c;
                    float sqv = fmaxf(fs_[fi][reg] + cs - 2.0f * d, 0.f);
                    out[NC + p]     = sqrtf(sqv) * SCALE_F;
                    out[2 * NC + p] = (d * SCALE_F) / (fn_[fi][reg] * cn);
                }
            }
        }
    }
}

// ---------------- L1 fallback: R8's exact kernel (f32, 2 insts/elem) -------
__device__ inline void add_abs(float& acc, float d) {
    asm("v_add_f32 %0, %0, abs(%1)" : "+v"(acc) : "v"(d));
}

__global__ __launch_bounds__(256)
void l1_main(const float* __restrict__ F, const float* __restrict__ Cc,
             float* __restrict__ out) {
    __shared__ float lds[2][192 * 16];

    const int tid = threadIdx.x;
    const int tx  = tid & 15;
    const int ty  = tid >> 4;
    const int c0  = blockIdx.x * 64;
    const int n0  = blockIdx.y * 128;

    const int srow  = tid >> 2;
    const int sslot = tid & 3;
    const int w16   = (tid >> 6) * 16;

    const float* fA = F + (size_t)(n0 + srow) * D_TOT + sslot * 4;
    const float* fB = fA + (size_t)64 * D_TOT;
    const int cswz  = sslot ^ ((srow >> 2) & 3);
    const float* cP = Cc + (size_t)(c0 + srow) * D_TOT + cswz * 4;
    const bool cok  = (c0 + srow) < C_TOT;

    f32x4 l1v[8];
    #pragma unroll
    for (int i = 0; i < 8; ++i) l1v[i] = (f32x4)(0.f);

    GL_LDS(fA, &lds[0][w16 * 16]);
    GL_LDS(fB, &lds[0][(64 + w16) * 16]);
    if (cok) GL_LDS(cP, &lds[0][(128 + w16) * 16]);
    __syncthreads();

    const int NT  = 32;
    const int crs = (tx >> 2) & 3;

    for (int t = 0; t < NT; ++t) {
        if (t + 1 < NT) {
            const int nb = (t + 1) & 1;
            const int d1 = (t + 1) * 16;
            GL_LDS(fA + d1, &lds[nb][w16 * 16]);
            GL_LDS(fB + d1, &lds[nb][(64 + w16) * 16]);
            if (cok) GL_LDS(cP + d1, &lds[nb][(128 + w16) * 16]);
        }

        const float* lf = &lds[t & 1][0];
        #pragma unroll
        for (int q = 0; q < 4; ++q) {
            const int cq = (q ^ crs) << 2;
            f32x4 cv0 = *(const f32x4*)&lf[(128 + tx) * 16 + cq];
            f32x4 cv1 = *(const f32x4*)&lf[(128 + tx + 16) * 16 + cq];
            f32x4 cv2 = *(const f32x4*)&lf[(128 + tx + 32) * 16 + cq];
            f32x4 cv3 = *(const f32x4*)&lf[(128 + tx + 48) * 16 + cq];
            #pragma unroll
            for (int i = 0; i < 8; ++i) {
                f32x4 fv = *(const f32x4*)&lf[((ty + 16 * i) << 4) + (q << 2)];
                float a0 = l1v[i][0], a1 = l1v[i][1];
                float a2 = l1v[i][2], a3 = l1v[i][3];
                #pragma unroll
                for (int k = 0; k < 4; ++k) {
                    add_abs(a0, fv[k] - cv0[k]);
                    add_abs(a1, fv[k] - cv1[k]);
                    add_abs(a2, fv[k] - cv2[k]);
                    add_abs(a3, fv[k] - cv3[k]);
                }
                l1v[i][0] = a0; l1v[i][1] = a1;
                l1v[i][2] = a2; l1v[i][3] = a3;
            }
        }
        __syncthreads();
    }

    #pragma unroll
    for (int i = 0; i < 8; ++i) {
        const size_t rb = (size_t)(n0 + ty + 16 * i) * C_TOT;
        #pragma unroll
        for (int j = 0; j < 4; ++j) {
            const int c = c0 + tx + 16 * j;
            if (c < C_TOT) out[rb + c] = l1v[i][j] * SCALE_F;
        }
    }
}

// ---------------- L1 fast path: packed f16, 1.5 insts/elem ----------------
// f16 LDS tiles, BD=32 (rows of 64 B, same bank geometry as R8: measured 0
// conflicts). C source-swizzled slot s ^ ((r>>2)&3); F unswizzled; reader
// applies crs=(tx>>2)&3 on C only. Per 8 elems: pk_sub(neg) + and + pk_acc.
// Packed f16 accumulator flushed per (j, tile) = 16 pk-adds max (drift
// ~0.12 pre-scale vs 13.8 budget) via one fdot2 (quarter-rate OK: 1/32 elems).
__global__ __launch_bounds__(256)
void l1_f16(const short* __restrict__ Ff16, const short* __restrict__ Cf16,
            float* __restrict__ out) {
    __shared__ char lds[2][192 * 64];

    const int tid = threadIdx.x;
    const int tx  = tid & 15;
    const int ty  = tid >> 4;
    const int c0  = blockIdx.x * 64;
    const int n0  = blockIdx.y * 128;

    const int r0 = tid >> 2;
    const int s0 = tid & 3;
    const int w16 = (tid >> 6) * 16;

    const short* gF0 = Ff16 + (size_t)(n0 + r0) * D_TOT + s0 * 8;
    const short* gF1 = gF0 + (size_t)64 * D_TOT;
    const int cswz   = s0 ^ ((r0 >> 2) & 3);
    const short* gC  = Cf16 + (size_t)(c0 + r0) * D_TOT + cswz * 8;  // zero-padded

    f32x4 l1v[8];
    #pragma unroll
    for (int i = 0; i < 8; ++i) l1v[i] = (f32x4)(0.f);

    GL_LDS(gF0, &lds[0][w16 * 64]);
    GL_LDS(gF1, &lds[0][(64 + w16) * 64]);
    GL_LDS(gC,  &lds[0][(128 + w16) * 64]);
    __syncthreads();

    const int NT  = 16;            // BD = 32 f16 per tile
    const int crs = (tx >> 2) & 3;
    const h2 ones = {(_Float16)1.0f, (_Float16)1.0f};

    for (int t = 0; t < NT; ++t) {
        if (t + 1 < NT) {
            const int nb = (t + 1) & 1;
            const int d1 = (t + 1) * 32;
            GL_LDS(gF0 + d1, &lds[nb][w16 * 64]);
            GL_LDS(gF1 + d1, &lds[nb][(64 + w16) * 64]);
            GL_LDS(gC + d1,  &lds[nb][(128 + w16) * 64]);
        }

        const char* lf = lds[t & 1];
        #pragma unroll
        for (int j = 0; j < 4; ++j) {
            unsigned accp[8];
            #pragma unroll
            for (int i = 0; i < 8; ++i) accp[i] = 0u;
            #pragma unroll
            for (int q = 0; q < 4; ++q) {
                u32x4 cw = *(const u32x4*)(lf + (128 + tx + 16 * j) * 64 +
                                           ((q ^ crs) << 4));
                #pragma unroll
                for (int i = 0; i < 8; ++i) {
                    u32x4 fw = *(const u32x4*)(lf + (ty + 16 * i) * 64 + (q << 4));
                    #pragma unroll
                    for (int m = 0; m < 4; ++m) {
                        unsigned d;
                        asm("v_pk_add_f16 %0, %1, %2 neg_lo:[0,1] neg_hi:[0,1]"
                            : "=v"(d) : "v"(fw[m]), "v"(cw[m]));
                        d &= 0x7FFF7FFFu;
                        asm("v_pk_add_f16 %0, %0, %1"
                            : "+v"(accp[i]) : "v"(d));
                    }
                }
            }
            #pragma unroll
            for (int i = 0; i < 8; ++i)
                l1v[i][j] = __builtin_amdgcn_fdot2(
                    __builtin_bit_cast(h2, accp[i]), ones, l1v[i][j], false);
        }
        __syncthreads();
    }

    #pragma unroll
    for (int i = 0; i < 8; ++i) {
        const size_t rb = (size_t)(n0 + ty + 16 * i) * C_TOT;
        #pragma unroll
        for (int j = 0; j < 4; ++j) {
            const int c = c0 + tx + 16 * j;
            if (c < C_TOT) out[rb + c] = l1v[i][j] * SCALE_F;
        }
    }
}

extern "C" void kernel_launch(void* const* d_in, const int* in_sizes, int n_in,
                              void* d_out, int out_size, void* d_ws, size_t ws_size,
                              hipStream_t stream) {
    const float* F  = (const float*)d_in[0];
    const float* Cc = (const float*)d_in[1];
    float* out   = (float*)d_out;
    char*  wsb   = (char*)d_ws;
    float* sqbuf = (float*)wsb;                  // [N_TOT + C_TOT] f32

    // bf16 scratch for dot_gemm parked in the not-yet-written L1 region of
    // out (R4-validated placement; dot_gemm consumes it before l1 overwrites).
    short* Fbf = (short*)out;
    short* Cbf = Fbf + (size_t)N_TOT * D_TOT;

    // f16 copies for the L1 fast path live in d_ws (guarded by ws_size).
    const size_t F16_OFF = 131072;  // leave sqbuf + pad
    short* Ff16 = (short*)(wsb + F16_OFF);
    short* Cf16 = Ff16 + (size_t)N_TOT * D_TOT;
    const size_t ws_need = F16_OFF + (size_t)(N_TOT + C_PAD) * D_TOT * 2;
    const bool fast = ws_size >= ws_need;

    int rows = N_TOT + C_TOT;
    int cvt_grid = (N_TOT * D_TOT / 8 + C_PAD * D_TOT / 8 + 255) / 256;
    sq_kernel<<<(rows + 3) / 4, 256, 0, stream>>>(F, Cc, sqbuf);
    cvt_kernel<<<cvt_grid, 256, 0, stream>>>(F, Cc, Fbf, Cbf);
    if (fast)
        cvt16_kernel<<<cvt_grid, 256, 0, stream>>>(F, Cc, Ff16, Cf16);
    dot_gemm<<<dim3(8, 128), 256, 0, stream>>>(Fbf, Cbf, sqbuf, out);
    if (fast)
        l1_f16<<<dim3(16, 128), 256, 0, stream>>>(Ff16, Cf16, out);
    else
        l1_main<<<dim3(16, 128), 256, 0, stream>>>(F, Cc, out);
}

// Round 12
// 458.799 us; speedup vs baseline: 1.0744x; 1.0129x over previous
//
#include <hip/hip_runtime.h>
#include <math.h>

typedef float    f32x4 __attribute__((ext_vector_type(4)));
typedef unsigned u32x4 __attribute__((ext_vector_type(4)));
typedef short    s16x8 __attribute__((ext_vector_type(8)));
typedef _Float16 h2    __attribute__((ext_vector_type(2)));

#define N_TOT 16384
#define C_TOT 1000
#define C_PAD 1024
#define D_TOT 512
#define NC ((size_t)N_TOT * C_TOT)

#define EPS_F 1e-8f
#define SCALE_F 0.04419417382415922f  // 1/sqrt(512)

#define GL_LDS(gp, lp)                                                        \
    __builtin_amdgcn_global_load_lds(                                         \
        (const __attribute__((address_space(1))) void*)(gp),                  \
        (__attribute__((address_space(3))) void*)(lp), 16, 0, 0)

// ---------------- fsq / csq precompute: one wave per row ----------------
__global__ __launch_bounds__(256)
void sq_kernel(const float* __restrict__ F, const float* __restrict__ Cc,
               float* __restrict__ sqout) {
    int gw   = (blockIdx.x * 256 + threadIdx.x) >> 6;
    int lane = threadIdx.x & 63;
    if (gw >= N_TOT + C_TOT) return;
    const float* src = (gw < N_TOT) ? (F + (size_t)gw * D_TOT)
                                    : (Cc + (size_t)(gw - N_TOT) * D_TOT);
    f32x4 a = *(const f32x4*)(src + lane * 4);
    f32x4 b = *(const f32x4*)(src + 256 + lane * 4);
    float acc = a[0] * a[0];
    acc = fmaf(a[1], a[1], acc);
    acc = fmaf(a[2], a[2], acc);
    acc = fmaf(a[3], a[3], acc);
    acc = fmaf(b[0], b[0], acc);
    acc = fmaf(b[1], b[1], acc);
    acc = fmaf(b[2], b[2], acc);
    acc = fmaf(b[3], b[3], acc);
    #pragma unroll
    for (int off = 32; off > 0; off >>= 1)
        acc += __shfl_xor(acc, off);
    if (lane == 0) sqout[gw] = acc;
}

// ---------------- f32 -> bf16 (RNE) convert, C zero-padded to 1024 rows ----
__device__ inline short f2bf(float x) {
    union { float f; unsigned u; } v; v.f = x;
    unsigned r = (v.u + 0x7FFFu + ((v.u >> 16) & 1u)) >> 16;
    return (short)r;
}

__global__ __launch_bounds__(256)
void cvt_kernel(const float* __restrict__ F, const float* __restrict__ Cc,
                short* __restrict__ Fbf, short* __restrict__ Cbf) {
    const int FS8 = N_TOT * D_TOT / 8;   // 1048576
    const int CS8 = C_PAD * D_TOT / 8;   // 65536
    int gid = blockIdx.x * 256 + threadIdx.x;
    if (gid < FS8) {
        const float* s = F + (size_t)gid * 8;
        f32x4 a = *(const f32x4*)s;
        f32x4 b = *(const f32x4*)(s + 4);
        s16x8 o;
        o[0] = f2bf(a[0]); o[1] = f2bf(a[1]); o[2] = f2bf(a[2]); o[3] = f2bf(a[3]);
        o[4] = f2bf(b[0]); o[5] = f2bf(b[1]); o[6] = f2bf(b[2]); o[7] = f2bf(b[3]);
        *(s16x8*)(Fbf + (size_t)gid * 8) = o;
    } else if (gid < FS8 + CS8) {
        int j = gid - FS8;
        int base = j * 8;
        int crow = base >> 9;
        s16x8 o = (s16x8)(short)0;
        if (crow < C_TOT) {
            const float* s = Cc + (size_t)base;
            f32x4 a = *(const f32x4*)s;
            f32x4 b = *(const f32x4*)(s + 4);
            o[0] = f2bf(a[0]); o[1] = f2bf(a[1]); o[2] = f2bf(a[2]); o[3] = f2bf(a[3]);
            o[4] = f2bf(b[0]); o[5] = f2bf(b[1]); o[6] = f2bf(b[2]); o[7] = f2bf(b[3]);
        }
        *(s16x8*)(Cbf + (size_t)base) = o;
    }
}

// ---------------- f32 -> f16 (RTZ pkrtz) copies for the L1 kernel ----------
__global__ __launch_bounds__(256)
void cvt16_kernel(const float* __restrict__ F, const float* __restrict__ Cc,
                  short* __restrict__ Ff16, short* __restrict__ Cf16) {
    const int FS8 = N_TOT * D_TOT / 8;
    const int CS8 = C_PAD * D_TOT / 8;
    int gid = blockIdx.x * 256 + threadIdx.x;
    if (gid < FS8) {
        const float* s = F + (size_t)gid * 8;
        f32x4 a = *(const f32x4*)s;
        f32x4 b = *(const f32x4*)(s + 4);
        u32x4 w;
        w[0] = __builtin_bit_cast(unsigned, __builtin_amdgcn_cvt_pkrtz(a[0], a[1]));
        w[1] = __builtin_bit_cast(unsigned, __builtin_amdgcn_cvt_pkrtz(a[2], a[3]));
        w[2] = __builtin_bit_cast(unsigned, __builtin_amdgcn_cvt_pkrtz(b[0], b[1]));
        w[3] = __builtin_bit_cast(unsigned, __builtin_amdgcn_cvt_pkrtz(b[2], b[3]));
        *(u32x4*)(Ff16 + (size_t)gid * 8) = w;
    } else if (gid < FS8 + CS8) {
        int j = gid - FS8;
        int base = j * 8;
        int crow = base >> 9;
        u32x4 w = (u32x4)(0u);
        if (crow < C_TOT) {
            const float* s = Cc + (size_t)base;
            f32x4 a = *(const f32x4*)s;
            f32x4 b = *(const f32x4*)(s + 4);
            w[0] = __builtin_bit_cast(unsigned, __builtin_amdgcn_cvt_pkrtz(a[0], a[1]));
            w[1] = __builtin_bit_cast(unsigned, __builtin_amdgcn_cvt_pkrtz(a[2], a[3]));
            w[2] = __builtin_bit_cast(unsigned, __builtin_amdgcn_cvt_pkrtz(b[0], b[1]));
            w[3] = __builtin_bit_cast(unsigned, __builtin_amdgcn_cvt_pkrtz(b[2], b[3]));
        }
        *(u32x4*)(Cf16 + (size_t)base) = w;
    }
}

// ---------------- bf16 MFMA dot GEMM -> writes L2 and cos (R4-validated) ---
__global__ __launch_bounds__(256)
void dot_gemm(const short* __restrict__ Fbf, const short* __restrict__ Cbf,
              const float* __restrict__ sqbuf, float* __restrict__ out) {
    __shared__ short lds[2][8192];   // A: [0,4096), B: [4096,8192)

    const int tid  = threadIdx.x;
    const int lane = tid & 63;
    const int wid  = tid >> 6;
    const int wr   = wid >> 1;
    const int wc   = wid & 1;
    const int m0   = blockIdx.y * 128;
    const int n0   = blockIdx.x * 128;

    const int row0 = tid >> 2;
    const int row1 = row0 + 64;
    const int slot = tid & 3;
    const int sw0  = slot ^ ((row0 >> 1) & 3);
    const int sw1  = slot ^ ((row1 >> 1) & 3);
    const short* sA0 = Fbf + (size_t)(m0 + row0) * D_TOT + sw0 * 8;
    const short* sA1 = Fbf + (size_t)(m0 + row1) * D_TOT + sw1 * 8;
    const short* sB0 = Cbf + (size_t)(n0 + row0) * D_TOT + sw0 * 8;
    const short* sB1 = Cbf + (size_t)(n0 + row1) * D_TOT + sw1 * 8;

    int offA[4], offB[4];
    #pragma unroll
    for (int fi = 0; fi < 4; ++fi) {
        int R = wr * 64 + fi * 16 + (lane & 15);
        offA[fi] = R * 32 + (((lane >> 4) ^ ((R >> 1) & 3)) << 3);
    }
    #pragma unroll
    for (int fj = 0; fj < 4; ++fj) {
        int R = wc * 64 + fj * 16 + (lane & 15);
        offB[fj] = 4096 + R * 32 + (((lane >> 4) ^ ((R >> 1) & 3)) << 3);
    }

    f32x4 acc[4][4];
    #pragma unroll
    for (int fi = 0; fi < 4; ++fi)
        #pragma unroll
        for (int fj = 0; fj < 4; ++fj) acc[fi][fj] = (f32x4)(0.f);

    GL_LDS(sA0, &lds[0][(size_t)tid * 8]);
    GL_LDS(sA1, &lds[0][(size_t)(tid + 256) * 8]);
    GL_LDS(sB0, &lds[0][4096 + (size_t)tid * 8]);
    GL_LDS(sB1, &lds[0][4096 + (size_t)(tid + 256) * 8]);
    __syncthreads();

    const int NK = D_TOT / 32;   // 16
    for (int kt = 0; kt < NK; ++kt) {
        if (kt + 1 < NK) {
            const int nb = (kt + 1) & 1;
            const int d1 = (kt + 1) * 32;
            GL_LDS(sA0 + d1, &lds[nb][(size_t)tid * 8]);
            GL_LDS(sA1 + d1, &lds[nb][(size_t)(tid + 256) * 8]);
            GL_LDS(sB0 + d1, &lds[nb][4096 + (size_t)tid * 8]);
            GL_LDS(sB1 + d1, &lds[nb][4096 + (size_t)(tid + 256) * 8]);
        }
        const short* lb = lds[kt & 1];
        s16x8 af[4], bg[4];
        #pragma unroll
        for (int fi = 0; fi < 4; ++fi) af[fi] = *(const s16x8*)&lb[offA[fi]];
        #pragma unroll
        for (int fj = 0; fj < 4; ++fj) bg[fj] = *(const s16x8*)&lb[offB[fj]];
        #pragma unroll
        for (int fi = 0; fi < 4; ++fi)
            #pragma unroll
            for (int fj = 0; fj < 4; ++fj)
                acc[fi][fj] = __builtin_amdgcn_mfma_f32_16x16x32_bf16(
                    af[fi], bg[fj], acc[fi][fj], 0, 0, 0);
        __syncthreads();
    }

    // epilogue: D layout col = lane&15, row = 4*(lane>>4) + reg  [m89/m91]
    const float* csq = sqbuf + N_TOT;
    float fs_[4][4], fn_[4][4];
    #pragma unroll
    for (int fi = 0; fi < 4; ++fi)
        #pragma unroll
        for (int reg = 0; reg < 4; ++reg) {
            int m = m0 + wr * 64 + fi * 16 + ((lane >> 4) << 2) + reg;
            float v = sqbuf[m];
            fs_[fi][reg] = v;
            fn_[fi][reg] = fmaxf(sqrtf(v), EPS_F);
        }
    #pragma unroll
    for (int fj = 0; fj < 4; ++fj) {
        int c = n0 + wc * 64 + fj * 16 + (lane & 15);
        if (c < C_TOT) {
            float cs = csq[c];
            float cn = fmaxf(sqrtf(cs), EPS_F);
            #pragma unroll
            for (int fi = 0; fi < 4; ++fi) {
                int mrow = m0 + wr * 64 + fi * 16 + ((lane >> 4) << 2);
                #pragma unroll
                for (int reg = 0; reg < 4; ++reg) {
                    float d = acc[fi][fj][reg];
                    size_t p = (size_t)(mrow + reg) * C_TOT + c;
                    float sqv = fmaxf(fs_[fi][reg] + cs - 2.0f * d, 0.f);
                    out[NC + p]     = sqrtf(sqv) * SCALE_F;
                    out[2 * NC + p] = (d * SCALE_F) / (fn_[fi][reg] * cn);
                }
            }
        }
    }
}

// ---------------- L1 fallback: R8's exact kernel (f32, 2 insts/elem) -------
__device__ inline void add_abs(float& acc, float d) {
    asm("v_add_f32 %0, %0, abs(%1)" : "+v"(acc) : "v"(d));
}

__global__ __launch_bounds__(256)
void l1_main(const float* __restrict__ F, const float* __restrict__ Cc,
             float* __restrict__ out) {
    __shared__ float lds[2][192 * 16];

    const int tid = threadIdx.x;
    const int tx  = tid & 15;
    const int ty  = tid >> 4;
    const int c0  = blockIdx.x * 64;
    const int n0  = blockIdx.y * 128;

    const int srow  = tid >> 2;
    const int sslot = tid & 3;
    const int w16   = (tid >> 6) * 16;

    const float* fA = F + (size_t)(n0 + srow) * D_TOT + sslot * 4;
    const float* fB = fA + (size_t)64 * D_TOT;
    const int cswz  = sslot ^ ((srow >> 2) & 3);
    const float* cP = Cc + (size_t)(c0 + srow) * D_TOT + cswz * 4;
    const bool cok  = (c0 + srow) < C_TOT;

    f32x4 l1v[8];
    #pragma unroll
    for (int i = 0; i < 8; ++i) l1v[i] = (f32x4)(0.f);

    GL_LDS(fA, &lds[0][w16 * 16]);
    GL_LDS(fB, &lds[0][(64 + w16) * 16]);
    if (cok) GL_LDS(cP, &lds[0][(128 + w16) * 16]);
    __syncthreads();

    const int NT  = 32;
    const int crs = (tx >> 2) & 3;

    for (int t = 0; t < NT; ++t) {
        if (t + 1 < NT) {
            const int nb = (t + 1) & 1;
            const int d1 = (t + 1) * 16;
            GL_LDS(fA + d1, &lds[nb][w16 * 16]);
            GL_LDS(fB + d1, &lds[nb][(64 + w16) * 16]);
            if (cok) GL_LDS(cP + d1, &lds[nb][(128 + w16) * 16]);
        }

        const float* lf = &lds[t & 1][0];
        #pragma unroll
        for (int q = 0; q < 4; ++q) {
            const int cq = (q ^ crs) << 2;
            f32x4 cv0 = *(const f32x4*)&lf[(128 + tx) * 16 + cq];
            f32x4 cv1 = *(const f32x4*)&lf[(128 + tx + 16) * 16 + cq];
            f32x4 cv2 = *(const f32x4*)&lf[(128 + tx + 32) * 16 + cq];
            f32x4 cv3 = *(const f32x4*)&lf[(128 + tx + 48) * 16 + cq];
            #pragma unroll
            for (int i = 0; i < 8; ++i) {
                f32x4 fv = *(const f32x4*)&lf[((ty + 16 * i) << 4) + (q << 2)];
                float a0 = l1v[i][0], a1 = l1v[i][1];
                float a2 = l1v[i][2], a3 = l1v[i][3];
                #pragma unroll
                for (int k = 0; k < 4; ++k) {
                    add_abs(a0, fv[k] - cv0[k]);
                    add_abs(a1, fv[k] - cv1[k]);
                    add_abs(a2, fv[k] - cv2[k]);
                    add_abs(a3, fv[k] - cv3[k]);
                }
                l1v[i][0] = a0; l1v[i][1] = a1;
                l1v[i][2] = a2; l1v[i][3] = a3;
            }
        }
        __syncthreads();
    }

    #pragma unroll
    for (int i = 0; i < 8; ++i) {
        const size_t rb = (size_t)(n0 + ty + 16 * i) * C_TOT;
        #pragma unroll
        for (int j = 0; j < 4; ++j) {
            const int c = c0 + tx + 16 * j;
            if (c < C_TOT) out[rb + c] = l1v[i][j] * SCALE_F;
        }
    }
}

// ---------------- L1 fast path: packed f16, q-outer, accp[i][j] ------------
// Same LDS layout/swizzle as R11 (measured 0 conflicts). Restructured so each
// F u32x4 is read ONCE per tile (48 b128/tile vs R11's 144). Packed f16
// accumulators accp[i][j] (32 VGPRs, unroll-const indexed) collect 16 pk-adds
// per tile, then flush to f32 via one fdot2 each (R11-validated arithmetic).
__global__ __launch_bounds__(256)
void l1_f16(const short* __restrict__ Ff16, const short* __restrict__ Cf16,
            float* __restrict__ out) {
    __shared__ char lds[2][192 * 64];

    const int tid = threadIdx.x;
    const int tx  = tid & 15;
    const int ty  = tid >> 4;
    const int c0  = blockIdx.x * 64;
    const int n0  = blockIdx.y * 128;

    const int r0 = tid >> 2;
    const int s0 = tid & 3;
    const int w16 = (tid >> 6) * 16;

    const short* gF0 = Ff16 + (size_t)(n0 + r0) * D_TOT + s0 * 8;
    const short* gF1 = gF0 + (size_t)64 * D_TOT;
    const int cswz   = s0 ^ ((r0 >> 2) & 3);
    const short* gC  = Cf16 + (size_t)(c0 + r0) * D_TOT + cswz * 8;  // zero-padded

    f32x4 l1v[8];
    #pragma unroll
    for (int i = 0; i < 8; ++i) l1v[i] = (f32x4)(0.f);

    GL_LDS(gF0, &lds[0][w16 * 64]);
    GL_LDS(gF1, &lds[0][(64 + w16) * 64]);
    GL_LDS(gC,  &lds[0][(128 + w16) * 64]);
    __syncthreads();

    const int NT  = 16;            // BD = 32 f16 per tile
    const int crs = (tx >> 2) & 3;
    const h2 ones = {(_Float16)1.0f, (_Float16)1.0f};

    for (int t = 0; t < NT; ++t) {
        if (t + 1 < NT) {
            const int nb = (t + 1) & 1;
            const int d1 = (t + 1) * 32;
            GL_LDS(gF0 + d1, &lds[nb][w16 * 64]);
            GL_LDS(gF1 + d1, &lds[nb][(64 + w16) * 64]);
            GL_LDS(gC + d1,  &lds[nb][(128 + w16) * 64]);
        }

        const char* lf = lds[t & 1];
        unsigned accp[8][4];
        #pragma unroll
        for (int i = 0; i < 8; ++i)
            #pragma unroll
            for (int j = 0; j < 4; ++j) accp[i][j] = 0u;

        #pragma unroll
        for (int q = 0; q < 4; ++q) {
            u32x4 cw[4];
            #pragma unroll
            for (int j = 0; j < 4; ++j)
                cw[j] = *(const u32x4*)(lf + (128 + tx + 16 * j) * 64 +
                                        ((q ^ crs) << 4));
            #pragma unroll
            for (int i = 0; i < 8; ++i) {
                u32x4 fw = *(const u32x4*)(lf + (ty + 16 * i) * 64 + (q << 4));
                #pragma unroll
                for (int m = 0; m < 4; ++m) {
                    #pragma unroll
                    for (int j = 0; j < 4; ++j) {
                        unsigned d;
                        asm("v_pk_add_f16 %0, %1, %2 neg_lo:[0,1] neg_hi:[0,1]"
                            : "=v"(d) : "v"(fw[m]), "v"(cw[j][m]));
                        d &= 0x7FFF7FFFu;
                        asm("v_pk_add_f16 %0, %0, %1"
                            : "+v"(accp[i][j]) : "v"(d));
                    }
                }
            }
        }

        #pragma unroll
        for (int i = 0; i < 8; ++i)
            #pragma unroll
            for (int j = 0; j < 4; ++j)
                l1v[i][j] = __builtin_amdgcn_fdot2(
                    __builtin_bit_cast(h2, accp[i][j]), ones, l1v[i][j], false);
        __syncthreads();
    }

    #pragma unroll
    for (int i = 0; i < 8; ++i) {
        const size_t rb = (size_t)(n0 + ty + 16 * i) * C_TOT;
        #pragma unroll
        for (int j = 0; j < 4; ++j) {
            const int c = c0 + tx + 16 * j;
            if (c < C_TOT) out[rb + c] = l1v[i][j] * SCALE_F;
        }
    }
}

extern "C" void kernel_launch(void* const* d_in, const int* in_sizes, int n_in,
                              void* d_out, int out_size, void* d_ws, size_t ws_size,
                              hipStream_t stream) {
    const float* F  = (const float*)d_in[0];
    const float* Cc = (const float*)d_in[1];
    float* out   = (float*)d_out;
    char*  wsb   = (char*)d_ws;
    float* sqbuf = (float*)wsb;                  // [N_TOT + C_TOT] f32

    // bf16 scratch for dot_gemm parked in the not-yet-written L1 region of
    // out (R4-validated placement; dot_gemm consumes it before l1 overwrites).
    short* Fbf = (short*)out;
    short* Cbf = Fbf + (size_t)N_TOT * D_TOT;

    // f16 copies for the L1 fast path live in d_ws (guarded by ws_size).
    const size_t F16_OFF = 131072;  // leave sqbuf + pad
    short* Ff16 = (short*)(wsb + F16_OFF);
    short* Cf16 = Ff16 + (size_t)N_TOT * D_TOT;
    const size_t ws_need = F16_OFF + (size_t)(N_TOT + C_PAD) * D_TOT * 2;
    const bool fast = ws_size >= ws_need;

    int rows = N_TOT + C_TOT;
    int cvt_grid = (N_TOT * D_TOT / 8 + C_PAD * D_TOT / 8 + 255) / 256;
    sq_kernel<<<(rows + 3) / 4, 256, 0, stream>>>(F, Cc, sqbuf);
    cvt_kernel<<<cvt_grid, 256, 0, stream>>>(F, Cc, Fbf, Cbf);
    if (fast)
        cvt16_kernel<<<cvt_grid, 256, 0, stream>>>(F, Cc, Ff16, Cf16);
    dot_gemm<<<dim3(8, 128), 256, 0, stream>>>(Fbf, Cbf, sqbuf, out);
    if (fast)
        l1_f16<<<dim3(16, 128), 256, 0, stream>>>(Ff16, Cf16, out);
    else
        l1_main<<<dim3(16, 128), 256, 0, stream>>>(F, Cc, out);
}

// Round 13
// 370.158 us; speedup vs baseline: 1.3316x; 1.2395x over previous
//
#include <hip/hip_runtime.h>
#include <math.h>

typedef float f32x4 __attribute__((ext_vector_type(4)));
typedef short s16x8 __attribute__((ext_vector_type(8)));

#define N_TOT 16384
#define C_TOT 1000
#define C_PAD 1024
#define D_TOT 512
#define NC ((size_t)N_TOT * C_TOT)

#define EPS_F 1e-8f
#define SCALE_F 0.04419417382415922f  // 1/sqrt(512)

#define GL_LDS(gp, lp)                                                        \
    __builtin_amdgcn_global_load_lds(                                         \
        (const __attribute__((address_space(1))) void*)(gp),                  \
        (__attribute__((address_space(3))) void*)(lp), 16, 0, 0)

// ---- fused f32->bf16 convert + row sum-of-squares (one wave == one row) ----
// Thread gid handles 8 elems; 64 consecutive threads (one wave) cover exactly
// one 512-elem row, so the sq reduction is a wave shuffle in the same pass.
__device__ inline short f2bf(float x) {
    union { float f; unsigned u; } v; v.f = x;
    unsigned r = (v.u + 0x7FFFu + ((v.u >> 16) & 1u)) >> 16;
    return (short)r;
}

__global__ __launch_bounds__(256)
void cvt_sq_kernel(const float* __restrict__ F, const float* __restrict__ Cc,
                   short* __restrict__ Fbf, short* __restrict__ Cbf,
                   float* __restrict__ sqbuf) {
    const int FS8 = N_TOT * D_TOT / 8;   // 1048576
    const int CS8 = C_PAD * D_TOT / 8;   // 65536
    int gid  = blockIdx.x * 256 + threadIdx.x;
    int lane = threadIdx.x & 63;

    if (gid < FS8) {
        const float* s = F + (size_t)gid * 8;
        f32x4 a = *(const f32x4*)s;
        f32x4 b = *(const f32x4*)(s + 4);
        s16x8 o;
        o[0] = f2bf(a[0]); o[1] = f2bf(a[1]); o[2] = f2bf(a[2]); o[3] = f2bf(a[3]);
        o[4] = f2bf(b[0]); o[5] = f2bf(b[1]); o[6] = f2bf(b[2]); o[7] = f2bf(b[3]);
        *(s16x8*)(Fbf + (size_t)gid * 8) = o;
        float acc = a[0] * a[0];
        acc = fmaf(a[1], a[1], acc); acc = fmaf(a[2], a[2], acc);
        acc = fmaf(a[3], a[3], acc); acc = fmaf(b[0], b[0], acc);
        acc = fmaf(b[1], b[1], acc); acc = fmaf(b[2], b[2], acc);
        acc = fmaf(b[3], b[3], acc);
        #pragma unroll
        for (int off = 32; off > 0; off >>= 1)
            acc += __shfl_xor(acc, off);
        if (lane == 0) sqbuf[gid >> 6] = acc;   // row id = gid/64
    } else if (gid < FS8 + CS8) {
        int base = (gid - FS8) * 8;
        int crow = base >> 9;
        s16x8 o = (s16x8)(short)0;
        float acc = 0.f;
        if (crow < C_TOT) {
            const float* s = Cc + (size_t)base;
            f32x4 a = *(const f32x4*)s;
            f32x4 b = *(const f32x4*)(s + 4);
            o[0] = f2bf(a[0]); o[1] = f2bf(a[1]); o[2] = f2bf(a[2]); o[3] = f2bf(a[3]);
            o[4] = f2bf(b[0]); o[5] = f2bf(b[1]); o[6] = f2bf(b[2]); o[7] = f2bf(b[3]);
            acc = a[0] * a[0];
            acc = fmaf(a[1], a[1], acc); acc = fmaf(a[2], a[2], acc);
            acc = fmaf(a[3], a[3], acc); acc = fmaf(b[0], b[0], acc);
            acc = fmaf(b[1], b[1], acc); acc = fmaf(b[2], b[2], acc);
            acc = fmaf(b[3], b[3], acc);
        }
        *(s16x8*)(Cbf + (size_t)base) = o;
        #pragma unroll
        for (int off = 32; off > 0; off >>= 1)
            acc += __shfl_xor(acc, off);
        if (lane == 0 && crow < C_TOT) sqbuf[N_TOT + crow] = acc;
    }
}

// ---------------- bf16 MFMA dot GEMM -> writes L2 and cos (R4-validated) ---
__global__ __launch_bounds__(256)
void dot_gemm(const short* __restrict__ Fbf, const short* __restrict__ Cbf,
              const float* __restrict__ sqbuf, float* __restrict__ out) {
    __shared__ short lds[2][8192];   // A: [0,4096), B: [4096,8192)

    const int tid  = threadIdx.x;
    const int lane = tid & 63;
    const int wid  = tid >> 6;
    const int wr   = wid >> 1;
    const int wc   = wid & 1;
    const int m0   = blockIdx.y * 128;
    const int n0   = blockIdx.x * 128;

    const int row0 = tid >> 2;
    const int row1 = row0 + 64;
    const int slot = tid & 3;
    const int sw0  = slot ^ ((row0 >> 1) & 3);
    const int sw1  = slot ^ ((row1 >> 1) & 3);
    const short* sA0 = Fbf + (size_t)(m0 + row0) * D_TOT + sw0 * 8;
    const short* sA1 = Fbf + (size_t)(m0 + row1) * D_TOT + sw1 * 8;
    const short* sB0 = Cbf + (size_t)(n0 + row0) * D_TOT + sw0 * 8;
    const short* sB1 = Cbf + (size_t)(n0 + row1) * D_TOT + sw1 * 8;

    int offA[4], offB[4];
    #pragma unroll
    for (int fi = 0; fi < 4; ++fi) {
        int R = wr * 64 + fi * 16 + (lane & 15);
        offA[fi] = R * 32 + (((lane >> 4) ^ ((R >> 1) & 3)) << 3);
    }
    #pragma unroll
    for (int fj = 0; fj < 4; ++fj) {
        int R = wc * 64 + fj * 16 + (lane & 15);
        offB[fj] = 4096 + R * 32 + (((lane >> 4) ^ ((R >> 1) & 3)) << 3);
    }

    f32x4 acc[4][4];
    #pragma unroll
    for (int fi = 0; fi < 4; ++fi)
        #pragma unroll
        for (int fj = 0; fj < 4; ++fj) acc[fi][fj] = (f32x4)(0.f);

    GL_LDS(sA0, &lds[0][(size_t)tid * 8]);
    GL_LDS(sA1, &lds[0][(size_t)(tid + 256) * 8]);
    GL_LDS(sB0, &lds[0][4096 + (size_t)tid * 8]);
    GL_LDS(sB1, &lds[0][4096 + (size_t)(tid + 256) * 8]);
    __syncthreads();

    const int NK = D_TOT / 32;   // 16
    for (int kt = 0; kt < NK; ++kt) {
        if (kt + 1 < NK) {
            const int nb = (kt + 1) & 1;
            const int d1 = (kt + 1) * 32;
            GL_LDS(sA0 + d1, &lds[nb][(size_t)tid * 8]);
            GL_LDS(sA1 + d1, &lds[nb][(size_t)(tid + 256) * 8]);
            GL_LDS(sB0 + d1, &lds[nb][4096 + (size_t)tid * 8]);
            GL_LDS(sB1 + d1, &lds[nb][4096 + (size_t)(tid + 256) * 8]);
        }
        const short* lb = lds[kt & 1];
        s16x8 af[4], bg[4];
        #pragma unroll
        for (int fi = 0; fi < 4; ++fi) af[fi] = *(const s16x8*)&lb[offA[fi]];
        #pragma unroll
        for (int fj = 0; fj < 4; ++fj) bg[fj] = *(const s16x8*)&lb[offB[fj]];
        #pragma unroll
        for (int fi = 0; fi < 4; ++fi)
            #pragma unroll
            for (int fj = 0; fj < 4; ++fj)
                acc[fi][fj] = __builtin_amdgcn_mfma_f32_16x16x32_bf16(
                    af[fi], bg[fj], acc[fi][fj], 0, 0, 0);
        __syncthreads();
    }

    // epilogue: D layout col = lane&15, row = 4*(lane>>4) + reg  [m89/m91]
    const float* csq = sqbuf + N_TOT;
    float fs_[4][4], fn_[4][4];
    #pragma unroll
    for (int fi = 0; fi < 4; ++fi)
        #pragma unroll
        for (int reg = 0; reg < 4; ++reg) {
            int m = m0 + wr * 64 + fi * 16 + ((lane >> 4) << 2) + reg;
            float v = sqbuf[m];
            fs_[fi][reg] = v;
            fn_[fi][reg] = fmaxf(sqrtf(v), EPS_F);
        }
    #pragma unroll
    for (int fj = 0; fj < 4; ++fj) {
        int c = n0 + wc * 64 + fj * 16 + (lane & 15);
        if (c < C_TOT) {
            float cs = csq[c];
            float cn = fmaxf(sqrtf(cs), EPS_F);
            #pragma unroll
            for (int fi = 0; fi < 4; ++fi) {
                int mrow = m0 + wr * 64 + fi * 16 + ((lane >> 4) << 2);
                #pragma unroll
                for (int reg = 0; reg < 4; ++reg) {
                    float d = acc[fi][fj][reg];
                    size_t p = (size_t)(mrow + reg) * C_TOT + c;
                    float sqv = fmaxf(fs_[fi][reg] + cs - 2.0f * d, 0.f);
                    out[NC + p]     = sqrtf(sqv) * SCALE_F;
                    out[2 * NC + p] = (d * SCALE_F) / (fn_[fi][reg] * cn);
                }
            }
        }
    }
}

// ---------------- L1 kernel: R8's exact measured-best (340 us, VGPR 40) ----
__device__ inline void add_abs(float& acc, float d) {
    asm("v_add_f32 %0, %0, abs(%1)" : "+v"(acc) : "v"(d));
}

__global__ __launch_bounds__(256)
void l1_main(const float* __restrict__ F, const float* __restrict__ Cc,
             float* __restrict__ out) {
    __shared__ float lds[2][192 * 16];

    const int tid = threadIdx.x;
    const int tx  = tid & 15;
    const int ty  = tid >> 4;
    const int c0  = blockIdx.x * 64;
    const int n0  = blockIdx.y * 128;

    const int srow  = tid >> 2;
    const int sslot = tid & 3;
    const int w16   = (tid >> 6) * 16;

    const float* fA = F + (size_t)(n0 + srow) * D_TOT + sslot * 4;
    const float* fB = fA + (size_t)64 * D_TOT;
    const int cswz  = sslot ^ ((srow >> 2) & 3);
    const float* cP = Cc + (size_t)(c0 + srow) * D_TOT + cswz * 4;
    const bool cok  = (c0 + srow) < C_TOT;

    f32x4 l1v[8];
    #pragma unroll
    for (int i = 0; i < 8; ++i) l1v[i] = (f32x4)(0.f);

    GL_LDS(fA, &lds[0][w16 * 16]);
    GL_LDS(fB, &lds[0][(64 + w16) * 16]);
    if (cok) GL_LDS(cP, &lds[0][(128 + w16) * 16]);
    __syncthreads();

    const int NT  = 32;
    const int crs = (tx >> 2) & 3;

    for (int t = 0; t < NT; ++t) {
        if (t + 1 < NT) {
            const int nb = (t + 1) & 1;
            const int d1 = (t + 1) * 16;
            GL_LDS(fA + d1, &lds[nb][w16 * 16]);
            GL_LDS(fB + d1, &lds[nb][(64 + w16) * 16]);
            if (cok) GL_LDS(cP + d1, &lds[nb][(128 + w16) * 16]);
        }

        const float* lf = &lds[t & 1][0];
        #pragma unroll
        for (int q = 0; q < 4; ++q) {
            const int cq = (q ^ crs) << 2;
            f32x4 cv0 = *(const f32x4*)&lf[(128 + tx) * 16 + cq];
            f32x4 cv1 = *(const f32x4*)&lf[(128 + tx + 16) * 16 + cq];
            f32x4 cv2 = *(const f32x4*)&lf[(128 + tx + 32) * 16 + cq];
            f32x4 cv3 = *(const f32x4*)&lf[(128 + tx + 48) * 16 + cq];
            #pragma unroll
            for (int i = 0; i < 8; ++i) {
                f32x4 fv = *(const f32x4*)&lf[((ty + 16 * i) << 4) + (q << 2)];
                float a0 = l1v[i][0], a1 = l1v[i][1];
                float a2 = l1v[i][2], a3 = l1v[i][3];
                #pragma unroll
                for (int k = 0; k < 4; ++k) {
                    add_abs(a0, fv[k] - cv0[k]);
                    add_abs(a1, fv[k] - cv1[k]);
                    add_abs(a2, fv[k] - cv2[k]);
                    add_abs(a3, fv[k] - cv3[k]);
                }
                l1v[i][0] = a0; l1v[i][1] = a1;
                l1v[i][2] = a2; l1v[i][3] = a3;
            }
        }
        __syncthreads();
    }

    #pragma unroll
    for (int i = 0; i < 8; ++i) {
        const size_t rb = (size_t)(n0 + ty + 16 * i) * C_TOT;
        #pragma unroll
        for (int j = 0; j < 4; ++j) {
            const int c = c0 + tx + 16 * j;
            if (c < C_TOT) out[rb + c] = l1v[i][j] * SCALE_F;
        }
    }
}

extern "C" void kernel_launch(void* const* d_in, const int* in_sizes, int n_in,
                              void* d_out, int out_size, void* d_ws, size_t ws_size,
                              hipStream_t stream) {
    const float* F  = (const float*)d_in[0];
    const float* Cc = (const float*)d_in[1];
    float* out   = (float*)d_out;
    float* sqbuf = (float*)d_ws;                 // [N_TOT + C_TOT] f32

    // bf16 scratch parked in the (not-yet-written) L1 region of out:
    // 17.8 MB < NC*4 B = 65.5 MB; dot_gemm consumes it and writes only the
    // L2/cos regions; l1_main overwrites the L1 region afterwards.
    // (R4/R7/R8-validated placement.)
    short* Fbf = (short*)out;
    short* Cbf = Fbf + (size_t)N_TOT * D_TOT;

    int cvt_grid = (N_TOT * D_TOT / 8 + C_PAD * D_TOT / 8 + 255) / 256;
    cvt_sq_kernel<<<cvt_grid, 256, 0, stream>>>(F, Cc, Fbf, Cbf, sqbuf);
    dot_gemm<<<dim3(8, 128), 256, 0, stream>>>(Fbf, Cbf, sqbuf, out);
    l1_main<<<dim3(16, 128), 256, 0, stream>>>(F, Cc, out);
}

// Round 14
// 367.071 us; speedup vs baseline: 1.3428x; 1.0084x over previous
//
#include <hip/hip_runtime.h>
#include <math.h>

typedef float f32x4 __attribute__((ext_vector_type(4)));
typedef short s16x8 __attribute__((ext_vector_type(8)));

#define N_TOT 16384
#define C_TOT 1000
#define C_PAD 1024
#define D_TOT 512
#define NC ((size_t)N_TOT * C_TOT)

#define EPS_F 1e-8f
#define SCALE_F 0.04419417382415922f  // 1/sqrt(512)

#define GL_LDS(gp, lp)                                                        \
    __builtin_amdgcn_global_load_lds(                                         \
        (const __attribute__((address_space(1))) void*)(gp),                  \
        (__attribute__((address_space(3))) void*)(lp), 16, 0, 0)

// ---- fused f32->bf16 convert + row sum-of-squares (one wave == one row) ----
__device__ inline short f2bf(float x) {
    union { float f; unsigned u; } v; v.f = x;
    unsigned r = (v.u + 0x7FFFu + ((v.u >> 16) & 1u)) >> 16;
    return (short)r;
}

__global__ __launch_bounds__(256)
void cvt_sq_kernel(const float* __restrict__ F, const float* __restrict__ Cc,
                   short* __restrict__ Fbf, short* __restrict__ Cbf,
                   float* __restrict__ sqbuf) {
    const int FS8 = N_TOT * D_TOT / 8;   // 1048576
    const int CS8 = C_PAD * D_TOT / 8;   // 65536
    int gid  = blockIdx.x * 256 + threadIdx.x;
    int lane = threadIdx.x & 63;

    if (gid < FS8) {
        const float* s = F + (size_t)gid * 8;
        f32x4 a = *(const f32x4*)s;
        f32x4 b = *(const f32x4*)(s + 4);
        s16x8 o;
        o[0] = f2bf(a[0]); o[1] = f2bf(a[1]); o[2] = f2bf(a[2]); o[3] = f2bf(a[3]);
        o[4] = f2bf(b[0]); o[5] = f2bf(b[1]); o[6] = f2bf(b[2]); o[7] = f2bf(b[3]);
        *(s16x8*)(Fbf + (size_t)gid * 8) = o;
        float acc = a[0] * a[0];
        acc = fmaf(a[1], a[1], acc); acc = fmaf(a[2], a[2], acc);
        acc = fmaf(a[3], a[3], acc); acc = fmaf(b[0], b[0], acc);
        acc = fmaf(b[1], b[1], acc); acc = fmaf(b[2], b[2], acc);
        acc = fmaf(b[3], b[3], acc);
        #pragma unroll
        for (int off = 32; off > 0; off >>= 1)
            acc += __shfl_xor(acc, off);
        if (lane == 0) sqbuf[gid >> 6] = acc;   // row id = gid/64
    } else if (gid < FS8 + CS8) {
        int base = (gid - FS8) * 8;
        int crow = base >> 9;
        s16x8 o = (s16x8)(short)0;
        float acc = 0.f;
        if (crow < C_TOT) {
            const float* s = Cc + (size_t)base;
            f32x4 a = *(const f32x4*)s;
            f32x4 b = *(const f32x4*)(s + 4);
            o[0] = f2bf(a[0]); o[1] = f2bf(a[1]); o[2] = f2bf(a[2]); o[3] = f2bf(a[3]);
            o[4] = f2bf(b[0]); o[5] = f2bf(b[1]); o[6] = f2bf(b[2]); o[7] = f2bf(b[3]);
            acc = a[0] * a[0];
            acc = fmaf(a[1], a[1], acc); acc = fmaf(a[2], a[2], acc);
            acc = fmaf(a[3], a[3], acc); acc = fmaf(b[0], b[0], acc);
            acc = fmaf(b[1], b[1], acc); acc = fmaf(b[2], b[2], acc);
            acc = fmaf(b[3], b[3], acc);
        }
        *(s16x8*)(Cbf + (size_t)base) = o;
        #pragma unroll
        for (int off = 32; off > 0; off >>= 1)
            acc += __shfl_xor(acc, off);
        if (lane == 0 && crow < C_TOT) sqbuf[N_TOT + crow] = acc;
    }
}

// ---------------- bf16 MFMA dot GEMM -> writes L2 and cos (R4-validated) ---
__global__ __launch_bounds__(256)
void dot_gemm(const short* __restrict__ Fbf, const short* __restrict__ Cbf,
              const float* __restrict__ sqbuf, float* __restrict__ out) {
    __shared__ short lds[2][8192];   // A: [0,4096), B: [4096,8192)

    const int tid  = threadIdx.x;
    const int lane = tid & 63;
    const int wid  = tid >> 6;
    const int wr   = wid >> 1;
    const int wc   = wid & 1;
    const int m0   = blockIdx.y * 128;
    const int n0   = blockIdx.x * 128;

    const int row0 = tid >> 2;
    const int row1 = row0 + 64;
    const int slot = tid & 3;
    const int sw0  = slot ^ ((row0 >> 1) & 3);
    const int sw1  = slot ^ ((row1 >> 1) & 3);
    const short* sA0 = Fbf + (size_t)(m0 + row0) * D_TOT + sw0 * 8;
    const short* sA1 = Fbf + (size_t)(m0 + row1) * D_TOT + sw1 * 8;
    const short* sB0 = Cbf + (size_t)(n0 + row0) * D_TOT + sw0 * 8;
    const short* sB1 = Cbf + (size_t)(n0 + row1) * D_TOT + sw1 * 8;

    int offA[4], offB[4];
    #pragma unroll
    for (int fi = 0; fi < 4; ++fi) {
        int R = wr * 64 + fi * 16 + (lane & 15);
        offA[fi] = R * 32 + (((lane >> 4) ^ ((R >> 1) & 3)) << 3);
    }
    #pragma unroll
    for (int fj = 0; fj < 4; ++fj) {
        int R = wc * 64 + fj * 16 + (lane & 15);
        offB[fj] = 4096 + R * 32 + (((lane >> 4) ^ ((R >> 1) & 3)) << 3);
    }

    f32x4 acc[4][4];
    #pragma unroll
    for (int fi = 0; fi < 4; ++fi)
        #pragma unroll
        for (int fj = 0; fj < 4; ++fj) acc[fi][fj] = (f32x4)(0.f);

    GL_LDS(sA0, &lds[0][(size_t)tid * 8]);
    GL_LDS(sA1, &lds[0][(size_t)(tid + 256) * 8]);
    GL_LDS(sB0, &lds[0][4096 + (size_t)tid * 8]);
    GL_LDS(sB1, &lds[0][4096 + (size_t)(tid + 256) * 8]);
    __syncthreads();

    const int NK = D_TOT / 32;   // 16
    for (int kt = 0; kt < NK; ++kt) {
        if (kt + 1 < NK) {
            const int nb = (kt + 1) & 1;
            const int d1 = (kt + 1) * 32;
            GL_LDS(sA0 + d1, &lds[nb][(size_t)tid * 8]);
            GL_LDS(sA1 + d1, &lds[nb][(size_t)(tid + 256) * 8]);
            GL_LDS(sB0 + d1, &lds[nb][4096 + (size_t)tid * 8]);
            GL_LDS(sB1 + d1, &lds[nb][4096 + (size_t)(tid + 256) * 8]);
        }
        const short* lb = lds[kt & 1];
        s16x8 af[4], bg[4];
        #pragma unroll
        for (int fi = 0; fi < 4; ++fi) af[fi] = *(const s16x8*)&lb[offA[fi]];
        #pragma unroll
        for (int fj = 0; fj < 4; ++fj) bg[fj] = *(const s16x8*)&lb[offB[fj]];
        #pragma unroll
        for (int fi = 0; fi < 4; ++fi)
            #pragma unroll
            for (int fj = 0; fj < 4; ++fj)
                acc[fi][fj] = __builtin_amdgcn_mfma_f32_16x16x32_bf16(
                    af[fi], bg[fj], acc[fi][fj], 0, 0, 0);
        __syncthreads();
    }

    // epilogue: D layout col = lane&15, row = 4*(lane>>4) + reg  [m89/m91]
    const float* csq = sqbuf + N_TOT;
    float fs_[4][4], fn_[4][4];
    #pragma unroll
    for (int fi = 0; fi < 4; ++fi)
        #pragma unroll
        for (int reg = 0; reg < 4; ++reg) {
            int m = m0 + wr * 64 + fi * 16 + ((lane >> 4) << 2) + reg;
            float v = sqbuf[m];
            fs_[fi][reg] = v;
            fn_[fi][reg] = fmaxf(sqrtf(v), EPS_F);
        }
    #pragma unroll
    for (int fj = 0; fj < 4; ++fj) {
        int c = n0 + wc * 64 + fj * 16 + (lane & 15);
        if (c < C_TOT) {
            float cs = csq[c];
            float cn = fmaxf(sqrtf(cs), EPS_F);
            #pragma unroll
            for (int fi = 0; fi < 4; ++fi) {
                int mrow = m0 + wr * 64 + fi * 16 + ((lane >> 4) << 2);
                #pragma unroll
                for (int reg = 0; reg < 4; ++reg) {
                    float d = acc[fi][fj][reg];
                    size_t p = (size_t)(mrow + reg) * C_TOT + c;
                    float sqv = fmaxf(fs_[fi][reg] + cs - 2.0f * d, 0.f);
                    out[NC + p]     = sqrtf(sqv) * SCALE_F;
                    out[2 * NC + p] = (d * SCALE_F) / (fn_[fi][reg] * cn);
                }
            }
        }
    }
}

// ---------------- L1 kernel: 128x128 tile, 8x8/thread, add_abs asm ---------
// LDS rows of 16 f32 (64 B): rows 0..127 = F, 128..255 = C. C source-swizzled
// (slot s of row r holds k-slot s ^ ((r>>2)&3)); F unswizzled. Reader applies
// crs=(tx>>2)&3 on C reads only (j-invariant: row step 16 -> same (r>>2)&3).
// Per tile/thread: 64 b128 reads feed 2048 VALU insts (0.75 B/elem) -> VALU-
// bound (LDS pipe demand 15360 < VALU 20480 cyc per CU-advance at 4 w/SIMD).
__device__ inline void add_abs(float& acc, float d) {
    asm("v_add_f32 %0, %0, abs(%1)" : "+v"(acc) : "v"(d));
}

__global__ __launch_bounds__(256)
void l1_main(const float* __restrict__ F, const float* __restrict__ Cc,
             float* __restrict__ out) {
    __shared__ float lds[2][256 * 16];

    const int tid = threadIdx.x;
    const int tx  = tid & 15;
    const int ty  = tid >> 4;
    const int c0  = blockIdx.x * 128;
    const int n0  = blockIdx.y * 128;

    const int row  = tid >> 2;         // 0..63
    const int slot = tid & 3;
    const int cswz = slot ^ ((row >> 2) & 3);   // same for row and row+64

    const float* sF0 = F + (size_t)(n0 + row) * D_TOT + slot * 4;
    const float* sF1 = sF0 + (size_t)64 * D_TOT;
    const float* sC0 = Cc + (size_t)(c0 + row) * D_TOT + cswz * 4;
    const float* sC1 = Cc + (size_t)(c0 + row + 64) * D_TOT + cswz * 4;
    const bool ok0 = (c0 + row) < C_TOT;
    const bool ok1 = (c0 + row + 64) < C_TOT;

    f32x4 l1a[8], l1b[8];   // j = 0..3 and 4..7
    #pragma unroll
    for (int i = 0; i < 8; ++i) { l1a[i] = (f32x4)(0.f); l1b[i] = (f32x4)(0.f); }

    GL_LDS(sF0, &lds[0][(size_t)tid * 4]);
    GL_LDS(sF1, &lds[0][(size_t)(tid + 256) * 4]);
    if (ok0) GL_LDS(sC0, &lds[0][(size_t)(tid + 512) * 4]);
    if (ok1) GL_LDS(sC1, &lds[0][(size_t)(tid + 768) * 4]);
    __syncthreads();

    const int NT  = 32;
    const int crs = (tx >> 2) & 3;

    for (int t = 0; t < NT; ++t) {
        if (t + 1 < NT) {
            const int nb = (t + 1) & 1;
            const int d1 = (t + 1) * 16;
            GL_LDS(sF0 + d1, &lds[nb][(size_t)tid * 4]);
            GL_LDS(sF1 + d1, &lds[nb][(size_t)(tid + 256) * 4]);
            if (ok0) GL_LDS(sC0 + d1, &lds[nb][(size_t)(tid + 512) * 4]);
            if (ok1) GL_LDS(sC1 + d1, &lds[nb][(size_t)(tid + 768) * 4]);
        }

        const float* lf = &lds[t & 1][0];
        #pragma unroll
        for (int q = 0; q < 4; ++q) {
            const int cq = (q ^ crs) << 2;
            f32x4 cv[8];
            #pragma unroll
            for (int j = 0; j < 8; ++j)
                cv[j] = *(const f32x4*)&lf[(128 + tx + 16 * j) * 16 + cq];
            #pragma unroll
            for (int i = 0; i < 8; ++i) {
                f32x4 fv = *(const f32x4*)&lf[((ty + 16 * i) << 4) + (q << 2)];
                float a0 = l1a[i][0], a1 = l1a[i][1];
                float a2 = l1a[i][2], a3 = l1a[i][3];
                float b0 = l1b[i][0], b1 = l1b[i][1];
                float b2 = l1b[i][2], b3 = l1b[i][3];
                #pragma unroll
                for (int k = 0; k < 4; ++k) {
                    add_abs(a0, fv[k] - cv[0][k]);
                    add_abs(a1, fv[k] - cv[1][k]);
                    add_abs(a2, fv[k] - cv[2][k]);
                    add_abs(a3, fv[k] - cv[3][k]);
                    add_abs(b0, fv[k] - cv[4][k]);
                    add_abs(b1, fv[k] - cv[5][k]);
                    add_abs(b2, fv[k] - cv[6][k]);
                    add_abs(b3, fv[k] - cv[7][k]);
                }
                l1a[i][0] = a0; l1a[i][1] = a1;
                l1a[i][2] = a2; l1a[i][3] = a3;
                l1b[i][0] = b0; l1b[i][1] = b1;
                l1b[i][2] = b2; l1b[i][3] = b3;
            }
        }
        __syncthreads();
    }

    #pragma unroll
    for (int i = 0; i < 8; ++i) {
        const size_t rb = (size_t)(n0 + ty + 16 * i) * C_TOT;
        #pragma unroll
        for (int j = 0; j < 4; ++j) {
            const int ca = c0 + tx + 16 * j;
            if (ca < C_TOT) out[rb + ca] = l1a[i][j] * SCALE_F;
            const int cb = c0 + tx + 16 * (j + 4);
            if (cb < C_TOT) out[rb + cb] = l1b[i][j] * SCALE_F;
        }
    }
}

extern "C" void kernel_launch(void* const* d_in, const int* in_sizes, int n_in,
                              void* d_out, int out_size, void* d_ws, size_t ws_size,
                              hipStream_t stream) {
    const float* F  = (const float*)d_in[0];
    const float* Cc = (const float*)d_in[1];
    float* out   = (float*)d_out;
    float* sqbuf = (float*)d_ws;                 // [N_TOT + C_TOT] f32

    // bf16 scratch parked in the (not-yet-written) L1 region of out:
    // 17.8 MB < NC*4 B = 65.5 MB; dot_gemm consumes it and writes only the
    // L2/cos regions; l1_main overwrites the L1 region afterwards.
    // (R4/R7/R8-validated placement.)
    short* Fbf = (short*)out;
    short* Cbf = Fbf + (size_t)N_TOT * D_TOT;

    int cvt_grid = (N_TOT * D_TOT / 8 + C_PAD * D_TOT / 8 + 255) / 256;
    cvt_sq_kernel<<<cvt_grid, 256, 0, stream>>>(F, Cc, Fbf, Cbf, sqbuf);
    dot_gemm<<<dim3(8, 128), 256, 0, stream>>>(Fbf, Cbf, sqbuf, out);
    l1_main<<<dim3(8, 128), 256, 0, stream>>>(F, Cc, out);
}